// Round 1
// baseline (431.028 us; speedup 1.0000x reference)
//
#include <hip/hip_runtime.h>

// Causal MHA: B=2, H=16, S=2048, DH=64. fp32 in/out. bf16 MFMA inside.
// R10: fused split-k fixup + VALU diet.
//  - combine kernel ELIMINATED: dynamic last-block-combines via per-pair
//    atomic counter + ready flag (canonical split-k fixup). First finisher
//    writes unnormalized partial + l, __threadfence, sets rdy; last finisher
//    spins (bounded: partner already past its atomic => resident & writing),
//    combines partner partial with its own REGISTERS, writes O. Saves the
//    combine dispatch + ~33 MB HBM round trip. prep zeroes the flags every
//    launch (ws is poisoned between runs). rocprof replay safe: if flags are
//    stale (=2), both blocks take the combine path, rdy==1 already -> no hang.
//  - l computed by ones-row MFMA (of_l = mfma(ones, bp, of_l)): 2 extra MFMA
//    per tile on the idle matrix pipe replaces 16 v_add + 2 shfl; l lands in
//    every lane for its own q-row, and is bf16-consistent with the numerator.
//  - exp2f -> __builtin_amdgcn_exp2f (single v_exp_f32, no OCML fixup code).
//  - prep lt transpose writes XOR-swizzled (16B-chunk ^ (d>>3)): 8-way -> 2-way.
// Kept from R9: split-k (2048 blocks, LPT order), fixed-max softmax (partials
// combine exactly), transposed GEMMs (St=K*Q^T, Ot=V^T*Pt), -M2 in MFMA C-init,
// v_perm Pt pack, LDP=72, prep kernel (bf16 Q*0.125*log2e, K, V^T), analytic
// causal mask, wave-local lgkmcnt fence. Fallback: whole-row kernel.

#define S_LEN  2048
#define DHDIM  64
#define NHEADS 32   // B*H
#define LDP    72   // padded LDS row length in shorts (144B = 9*16B)
#define M2     23.083120654223414f   // 16 * log2(e)
#define QSCALE 0.18033688011117658f  // 0.125 * log2(e)

typedef __attribute__((ext_vector_type(8))) short bf16x8;
typedef __attribute__((ext_vector_type(4))) float f32x4;

__device__ __forceinline__ float fast_exp2(float x) {
#if __has_builtin(__builtin_amdgcn_exp2f)
    return __builtin_amdgcn_exp2f(x);
#else
    return exp2f(x);
#endif
}
__device__ __forceinline__ unsigned short f2bf(float f) { // RNE
    unsigned u = __float_as_uint(f);
    return (unsigned short)((u + 0x7fffu + ((u >> 16) & 1u)) >> 16);
}
__device__ __forceinline__ void ld8(const float* p, float* f) {
    float4 a = *(const float4*)p, b = *(const float4*)(p + 4);
    f[0]=a.x; f[1]=a.y; f[2]=a.z; f[3]=a.w; f[4]=b.x; f[5]=b.y; f[6]=b.z; f[7]=b.w;
}
__device__ __forceinline__ uint4 pack8(const float* f, float scale) {
    union { uint4 v; unsigned short s[8]; } w;
    #pragma unroll
    for (int j = 0; j < 8; j++) w.s[j] = f2bf(f[j] * scale);
    return w.v;
}
// combine high-16s of two floats into one dword: [lo16=a.hi16, hi16=b.hi16]
__device__ __forceinline__ unsigned packhi(float a, float b) {
#if __has_builtin(__builtin_amdgcn_perm)
    return __builtin_amdgcn_perm(__float_as_uint(b), __float_as_uint(a), 0x07060302u);
#else
    return (__float_as_uint(a) >> 16) | (__float_as_uint(b) & 0xffff0000u);
#endif
}

// ---- pre-pass: per block (st, bh): V 64x64 tile -> bf16 V^T tile, plus a
// 4096-elem chunk of Q (scaled) and K -> bf16. Also zeroes split-k flags.
__global__ __launch_bounds__(256) void prep(
    const float* __restrict__ Qf, const float* __restrict__ Kf,
    const float* __restrict__ Vf, unsigned short* __restrict__ qb,
    unsigned short* __restrict__ kb, unsigned short* __restrict__ vtb,
    int* __restrict__ flags)
{
    const int st = blockIdx.x, bh = blockIdx.y;
    if (flags && threadIdx.x < 2)
        flags[threadIdx.x * 1024 + bh * 32 + st] = 0; // cnt / rdy for this pair
    __shared__ unsigned short lt[64][LDP];
    const float* vp = Vf + ((size_t)bh * S_LEN + st * 64) * DHDIM;
    for (int c = threadIdx.x; c < 512; c += 256) {
        int s = c >> 3, d0 = (c & 7) * 8;
        float f[8]; ld8(vp + s * DHDIM + d0, f);
        #pragma unroll
        for (int j = 0; j < 8; j++) {
            int d = d0 + j;
            // XOR-swizzle the 16B chunk index with d>>3: write conflicts 8-way -> 2-way
            int col = (s & 7) | ((((s >> 3) ^ (d >> 3)) & 7) << 3);
            lt[d][col] = f2bf(f[j]);
        }
    }
    size_t off = ((size_t)(bh * 32 + st) * 4096) + (size_t)threadIdx.x * 16;
    float f[8];
    ld8(Qf + off, f);     *(uint4*)(qb + off)     = pack8(f, QSCALE);
    ld8(Qf + off + 8, f); *(uint4*)(qb + off + 8) = pack8(f, QSCALE);
    ld8(Kf + off, f);     *(uint4*)(kb + off)     = pack8(f, 1.0f);
    ld8(Kf + off + 8, f); *(uint4*)(kb + off + 8) = pack8(f, 1.0f);
    __syncthreads();
    unsigned short* op = vtb + (size_t)bh * DHDIM * S_LEN + st * 64;
    for (int c = threadIdx.x; c < 512; c += 256) {
        int d = c >> 3, q = c & 7;
        int colc = ((q ^ (d >> 3)) & 7) << 3;  // matching read-side swizzle
        *(uint4*)(op + (size_t)d * S_LEN + q * 8) = *(const uint4*)&lt[d][colc];
    }
}

// ---- split-k main with fused fixup: block = (bh, qt, half).
__global__ __launch_bounds__(256) void fattn_splitk(
    const unsigned short* __restrict__ Qp, const unsigned short* __restrict__ Kp,
    const unsigned short* __restrict__ Vp,
    float* __restrict__ pO, float* __restrict__ pL,
    int* __restrict__ flags, float* __restrict__ O)
{
    __shared__ unsigned short smem[192 * LDP]; // 27.6 KB -> 5 blocks/CU
    __shared__ int s_old;
    unsigned short (*ks)[LDP]  = (unsigned short(*)[LDP])smem;
    unsigned short (*vts)[LDP] = (unsigned short(*)[LDP])(smem + 64 * LDP);
    unsigned short (*qs)[LDP]  = (unsigned short(*)[LDP])(smem + 128 * LDP);
    unsigned short (*pst)[LDP] = qs; // overlay: wave w touches only rows w*16..+15

    // longest-first (LPT) issue order: qt descending with id
    const int id   = blockIdx.y * 64 + blockIdx.x;   // 0..2047
    const int qt   = 31 - (id >> 6);
    const int rem  = id & 63;
    const int bh   = rem >> 1;
    const int half = rem & 1;
    const int kmid = (qt + 2) >> 1;                  // split point
    const int k0   = half ? kmid : 0;
    const int k1   = half ? qt + 1 : kmid;
    const int pair = bh * 32 + qt;
    const int slot = (pair << 1) | half;

    const int tid = threadIdx.x;
    const int wave = tid >> 6, lane = tid & 63;
    const int quad = lane >> 4, l16 = lane & 15;

    // ---- stage Q tile (bf16, pre-scaled by prep)
    {
        const unsigned short* src = Qp + ((size_t)bh * S_LEN + qt * 64) * DHDIM;
        for (int c = tid; c < 512; c += 256) {
            int row = c >> 3, c8 = (c & 7) * 8;
            *(uint4*)&qs[row][c8] = *(const uint4*)(src + row * DHDIM + c8);
        }
    }
    __syncthreads();

    const int prow = wave * 16 + l16; // this lane's q-row (transposed scheme)
    const bf16x8 bq0 = *(const bf16x8*)&qs[prow][quad * 8];
    const bf16x8 bq1 = *(const bf16x8*)&qs[prow][32 + quad * 8];

    bf16x8 ones;
    #pragma unroll
    for (int j = 0; j < 8; j++) ones[j] = (short)0x3F80; // bf16 1.0

    f32x4 of[4];
    f32x4 of_l = (f32x4){0.f, 0.f, 0.f, 0.f}; // row of ones * Pt = l per q-col
    #pragma unroll
    for (int n = 0; n < 4; n++) of[n] = (f32x4){0.f, 0.f, 0.f, 0.f};

    for (int kt = k0; kt < k1; kt++) {
        __syncthreads(); // prior iter done with ks/vts

        const unsigned short* ksrc = Kp + ((size_t)bh * S_LEN + kt * 64) * DHDIM;
        const unsigned short* vsrc = Vp + (size_t)bh * DHDIM * S_LEN + kt * 64;
        for (int c = tid; c < 512; c += 256) {
            int row = c >> 3, c8 = (c & 7) * 8;
            *(uint4*)&ks[row][c8]  = *(const uint4*)(ksrc + row * DHDIM + c8);
            *(uint4*)&vts[row][c8] = *(const uint4*)(vsrc + (size_t)row * S_LEN + c8);
        }
        __syncthreads();

        // ---- St tile n; C-init = -M2 folds the softmax subtract
        f32x4 sf[4];
        #pragma unroll
        for (int n = 0; n < 4; n++) {
            bf16x8 ak0 = *(const bf16x8*)&ks[n * 16 + l16][quad * 8];
            bf16x8 ak1 = *(const bf16x8*)&ks[n * 16 + l16][32 + quad * 8];
            sf[n] = (f32x4){-M2, -M2, -M2, -M2};
            sf[n] = __builtin_amdgcn_mfma_f32_16x16x32_bf16(ak0, bq0, sf[n], 0, 0, 0);
            sf[n] = __builtin_amdgcn_mfma_f32_16x16x32_bf16(ak1, bq1, sf[n], 0, 0, 0);
        }

        // ---- p = exp2(sf), causal zero (diag tile), pack Pt (l via MFMA below)
        const bool diag = (kt == qt);
        #pragma unroll
        for (int n = 0; n < 4; n++) {
            float p[4];
            #pragma unroll
            for (int r = 0; r < 4; r++) {
                p[r] = fast_exp2(sf[n][r]);
                if (diag && (n * 16 + quad * 4 + r > prow)) p[r] = 0.f;
            }
            uint2 dw;
            dw.x = packhi(p[0], p[1]); // bf16 truncation via byte-select
            dw.y = packhi(p[2], p[3]);
            *(uint2*)&pst[prow][n * 16 + quad * 4] = dw;
        }
        asm volatile("s_waitcnt lgkmcnt(0)" ::: "memory"); // wave-local Pt fence

        bf16x8 bp0 = *(const bf16x8*)&pst[prow][quad * 8];
        bf16x8 bp1 = *(const bf16x8*)&pst[prow][32 + quad * 8];
        of_l = __builtin_amdgcn_mfma_f32_16x16x32_bf16(ones, bp0, of_l, 0, 0, 0);
        of_l = __builtin_amdgcn_mfma_f32_16x16x32_bf16(ones, bp1, of_l, 0, 0, 0);
        #pragma unroll
        for (int n = 0; n < 4; n++) {
            bf16x8 av0 = *(const bf16x8*)&vts[n * 16 + l16][quad * 8];
            bf16x8 av1 = *(const bf16x8*)&vts[n * 16 + l16][32 + quad * 8];
            of[n] = __builtin_amdgcn_mfma_f32_16x16x32_bf16(av0, bp0, of[n], 0, 0, 0);
            of[n] = __builtin_amdgcn_mfma_f32_16x16x32_bf16(av1, bp1, of[n], 0, 0, 0);
        }
    }

    // ---- fused split-k fixup: dynamic last-block-combines
    int* cnt = flags;
    int* rdy = flags + 1024;
    if (tid == 0) s_old = atomicAdd(&cnt[pair], 1);
    __syncthreads();

    if (s_old == 0) {
        // first finisher: publish unnormalized partial + l, then signal
        if (quad == 0) pL[slot * 64 + prow] = of_l[0];
        float* op = pO + (size_t)slot * 4096 + prow * 64;
        #pragma unroll
        for (int n = 0; n < 4; n++)
            *(float4*)(op + n * 16 + quad * 4) =
                make_float4(of[n][0], of[n][1], of[n][2], of[n][3]);
        __threadfence();          // drain this thread's partial writes to LLC
        __syncthreads();          // all threads fenced
        if (tid == 0)
            __hip_atomic_store(&rdy[pair], 1, __ATOMIC_RELEASE,
                               __HIP_MEMORY_SCOPE_AGENT);
    } else {
        // last finisher: partner already past its atomic => resident & writing.
        if (tid == 0) {
            while (__hip_atomic_load(&rdy[pair], __ATOMIC_ACQUIRE,
                                     __HIP_MEMORY_SCOPE_AGENT) == 0)
                __builtin_amdgcn_s_sleep(2);
        }
        __syncthreads();
        __threadfence();          // acquire: invalidate caches before reads
        const int pslot = slot ^ 1;
        const float inv = 1.f / (of_l[0] + pL[pslot * 64 + prow]);
        const float* pp = pO + (size_t)pslot * 4096 + prow * 64;
        float* op = O + ((size_t)bh * S_LEN + qt * 64 + prow) * DHDIM;
        #pragma unroll
        for (int n = 0; n < 4; n++) {
            float4 a = *(const float4*)(pp + n * 16 + quad * 4);
            *(float4*)(op + n * 16 + quad * 4) = make_float4(
                (of[n][0] + a.x) * inv, (of[n][1] + a.y) * inv,
                (of[n][2] + a.z) * inv, (of[n][3] + a.w) * inv);
        }
    }
}

// ---- R8 fallback kernels (whole-row blocks), used when ws can't hold partials
template <bool PRE>
__global__ __launch_bounds__(256) void fattn_kernel(
    const void* __restrict__ Qp, const void* __restrict__ Kp,
    const void* __restrict__ Vp, float* __restrict__ O)
{
    __shared__ unsigned short smem[192 * LDP];
    unsigned short (*ks)[LDP]  = (unsigned short(*)[LDP])smem;
    unsigned short (*vts)[LDP] = (unsigned short(*)[LDP])(smem + 64 * LDP);
    unsigned short (*qs)[LDP]  = (unsigned short(*)[LDP])(smem + 128 * LDP);
    unsigned short (*pst)[LDP] = qs;

    const int id = blockIdx.y * 32 + blockIdx.x;
    const int g  = id >> 8;
    const int r8 = id & 255;
    const int bh = r8 >> 3;
    const int s8 = r8 & 7;
    const int qt = (g == 0) ? 31 - 2 * s8 : (g == 1) ? 2 * s8
                 : (g == 2) ? 30 - 2 * s8 : 2 * s8 + 1;

    const int tid = threadIdx.x;
    const int wave = tid >> 6, lane = tid & 63;
    const int quad = lane >> 4, l16 = lane & 15;

    if constexpr (PRE) {
        const unsigned short* src = (const unsigned short*)Qp
            + ((size_t)bh * S_LEN + qt * 64) * DHDIM;
        for (int c = tid; c < 512; c += 256) {
            int row = c >> 3, c8 = (c & 7) * 8;
            *(uint4*)&qs[row][c8] = *(const uint4*)(src + row * DHDIM + c8);
        }
    } else {
        const float* src = (const float*)Qp + ((size_t)bh * S_LEN + qt * 64) * DHDIM;
        for (int c = tid; c < 512; c += 256) {
            int row = c >> 3, c8 = (c & 7) * 8;
            float f[8]; ld8(src + row * DHDIM + c8, f);
            *(uint4*)&qs[row][c8] = pack8(f, QSCALE);
        }
    }
    __syncthreads();

    const int prow = wave * 16 + l16;
    const bf16x8 bq0 = *(const bf16x8*)&qs[prow][quad * 8];
    const bf16x8 bq1 = *(const bf16x8*)&qs[prow][32 + quad * 8];

    float l_p = 0.f;
    f32x4 of[4];
    #pragma unroll
    for (int n = 0; n < 4; n++) of[n] = (f32x4){0.f, 0.f, 0.f, 0.f};

    for (int kt = 0; kt <= qt; kt++) {
        __syncthreads();
        if constexpr (PRE) {
            const unsigned short* ksrc = (const unsigned short*)Kp
                + ((size_t)bh * S_LEN + kt * 64) * DHDIM;
            const unsigned short* vsrc = (const unsigned short*)Vp
                + (size_t)bh * DHDIM * S_LEN + kt * 64;
            for (int c = tid; c < 512; c += 256) {
                int row = c >> 3, c8 = (c & 7) * 8;
                *(uint4*)&ks[row][c8]  = *(const uint4*)(ksrc + row * DHDIM + c8);
                *(uint4*)&vts[row][c8] = *(const uint4*)(vsrc + (size_t)row * S_LEN + c8);
            }
        } else {
            const float* ksrc = (const float*)Kp + ((size_t)bh * S_LEN + kt * 64) * DHDIM;
            const float* vsrc = (const float*)Vp + ((size_t)bh * S_LEN + kt * 64) * DHDIM;
            for (int c = tid; c < 512; c += 256) {
                int row = c >> 3, c8 = (c & 7) * 8;
                float f[8];
                ld8(ksrc + row * DHDIM + c8, f);
                *(uint4*)&ks[row][c8] = pack8(f, 1.0f);
                ld8(vsrc + row * DHDIM + c8, f);
                #pragma unroll
                for (int j = 0; j < 8; j++) vts[c8 + j][row] = f2bf(f[j]);
            }
        }
        __syncthreads();

        f32x4 sf[4];
        #pragma unroll
        for (int n = 0; n < 4; n++) {
            bf16x8 ak0 = *(const bf16x8*)&ks[n * 16 + l16][quad * 8];
            bf16x8 ak1 = *(const bf16x8*)&ks[n * 16 + l16][32 + quad * 8];
            sf[n] = (f32x4){-M2, -M2, -M2, -M2};
            sf[n] = __builtin_amdgcn_mfma_f32_16x16x32_bf16(ak0, bq0, sf[n], 0, 0, 0);
            sf[n] = __builtin_amdgcn_mfma_f32_16x16x32_bf16(ak1, bq1, sf[n], 0, 0, 0);
        }

        const bool diag = (kt == qt);
        #pragma unroll
        for (int n = 0; n < 4; n++) {
            float p[4];
            #pragma unroll
            for (int r = 0; r < 4; r++) {
                p[r] = fast_exp2(sf[n][r]);
                if (diag && (n * 16 + quad * 4 + r > prow)) p[r] = 0.f;
                l_p += p[r];
            }
            uint2 dw;
            dw.x = packhi(p[0], p[1]);
            dw.y = packhi(p[2], p[3]);
            *(uint2*)&pst[prow][n * 16 + quad * 4] = dw;
        }
        asm volatile("s_waitcnt lgkmcnt(0)" ::: "memory");

        bf16x8 bp0 = *(const bf16x8*)&pst[prow][quad * 8];
        bf16x8 bp1 = *(const bf16x8*)&pst[prow][32 + quad * 8];
        #pragma unroll
        for (int n = 0; n < 4; n++) {
            bf16x8 av0 = *(const bf16x8*)&vts[n * 16 + l16][quad * 8];
            bf16x8 av1 = *(const bf16x8*)&vts[n * 16 + l16][32 + quad * 8];
            of[n] = __builtin_amdgcn_mfma_f32_16x16x32_bf16(av0, bp0, of[n], 0, 0, 0);
            of[n] = __builtin_amdgcn_mfma_f32_16x16x32_bf16(av1, bp1, of[n], 0, 0, 0);
        }
    }

    l_p += __shfl_xor(l_p, 16);
    l_p += __shfl_xor(l_p, 32);
    const float inv = 1.f / l_p;
    float* op = O + ((size_t)bh * S_LEN + qt * 64 + prow) * DHDIM;
    #pragma unroll
    for (int n = 0; n < 4; n++)
        *(float4*)(op + n * 16 + quad * 4) = make_float4(
            of[n][0] * inv, of[n][1] * inv, of[n][2] * inv, of[n][3] * inv);
}

extern "C" void kernel_launch(void* const* d_in, const int* in_sizes, int n_in,
                              void* d_out, int out_size, void* d_ws, size_t ws_size,
                              hipStream_t stream) {
    const float* Q = (const float*)d_in[0];
    const float* K = (const float*)d_in[1];
    const float* V = (const float*)d_in[2];
    // d_in[3] = causal mask: analytic, not read.
    float* O = (float*)d_out;
    const size_t N = (size_t)NHEADS * S_LEN * DHDIM;      // 4,194,304 elems
    const size_t prepB  = 3 * N * sizeof(unsigned short); // 25.2 MB
    const size_t partB  = (size_t)2048 * (4096 + 64) * sizeof(float); // 34.1 MB
    const size_t flagB  = 2048 * sizeof(int);             // cnt[1024] + rdy[1024]

    if (d_ws && ws_size >= prepB + partB + flagB) {
        unsigned short* qb  = (unsigned short*)d_ws;
        unsigned short* kb  = qb + N;
        unsigned short* vtb = kb + N;
        float* pO = (float*)((char*)d_ws + prepB);
        float* pL = pO + (size_t)2048 * 4096;
        int* flags = (int*)((char*)d_ws + prepB + partB);
        prep<<<dim3(S_LEN / 64, NHEADS), 256, 0, stream>>>(Q, K, V, qb, kb, vtb, flags);
        fattn_splitk<<<dim3(64, 32), 256, 0, stream>>>(qb, kb, vtb, pO, pL, flags, O);
    } else if (d_ws && ws_size >= prepB) {
        unsigned short* qb  = (unsigned short*)d_ws;
        unsigned short* kb  = qb + N;
        unsigned short* vtb = kb + N;
        prep<<<dim3(S_LEN / 64, NHEADS), 256, 0, stream>>>(Q, K, V, qb, kb, vtb, nullptr);
        fattn_kernel<true><<<dim3(32, 32), 256, 0, stream>>>(qb, kb, vtb, O);
    } else {
        fattn_kernel<false><<<dim3(32, 32), 256, 0, stream>>>(Q, K, V, O);
    }
}

// Round 2
// 144.775 us; speedup vs baseline: 2.9772x; 2.9772x over previous
//
#include <hip/hip_runtime.h>

// Causal MHA: B=2, H=16, S=2048, DH=64. fp32 in/out. bf16 MFMA inside.
// R11: revert R10's fused fixup (per-block agent-scope fences = L2
// writeback/invalidate storm, 7x regression). Back to 3-kernel structure.
// Kept from R10 (verified correct, absmax improved to 0.0156):
//  - fast_exp2 (__builtin_amdgcn_exp2f, single v_exp_f32)
//  - l via ones-row MFMA (of_l = mfma(ones, bp, of_l)) on the idle matrix
//    pipe; kills 16 v_add + 2 shfl per tile; l lands per-lane for its q-row
//  - prep lt transpose-write XOR swizzle (8-way -> 2-way)
// NEW: selective split-k. Only qt>=16 rows are split in two (their halves are
// length 8..16); qt<16 rows (length <=16 <= makespan bound) run whole and
// write O directly (normalized). 1536 blocks, static LPT table, longest-first
// dispatch order. Halves combine traffic: pO slots 2048->1024 (16.8 MB),
// combine kernel reads/writes half of before.
// Kept from R9: fixed-max softmax (partials combine EXACTLY: O=(Oa+Ob)/(la+lb)),
// transposed GEMMs (St=K*Q^T, Ot=V^T*Pt), -M2 folded into MFMA C-init, v_perm
// Pt pack, LDP=72, prep kernel (bf16 Q*0.125*log2e, K, V^T), analytic causal
// mask, wave-local lgkmcnt fence. Fallback: whole-row kernel if ws too small.

#define S_LEN  2048
#define DHDIM  64
#define NHEADS 32   // B*H
#define LDP    72   // padded LDS row length in shorts (144B = 9*16B)
#define M2     23.083120654223414f   // 16 * log2(e)
#define QSCALE 0.18033688011117658f  // 0.125 * log2(e)

typedef __attribute__((ext_vector_type(8))) short bf16x8;
typedef __attribute__((ext_vector_type(4))) float f32x4;

// static LPT schedule: 48 items per bh, descending length.
// splits for qt in [16,31] (kmid=(qt+2)>>1), wholes for qt in [0,15].
__device__ __constant__ unsigned char T_QT[48] = {
    31,31,30,15, 30,29,29,28,14, 28,27,27,26,13, 26,25,25,24,12,
    24,23,23,22,11, 22,21,21,20,10, 20,19,19,18,9, 18,17,17,16,8,
    16,7, 6,5,4,3,2,1,0};
__device__ __constant__ unsigned char T_K0[48] = {
    0,16,0,0, 16,0,15,0,0, 15,0,14,0,0, 14,0,13,0,0,
    13,0,12,0,0, 12,0,11,0,0, 11,0,10,0,0, 10,0,9,0,0,
    9,0, 0,0,0,0,0,0,0};
__device__ __constant__ unsigned char T_K1[48] = {
    16,32,16,16, 31,15,30,15,15, 29,14,28,14,14, 27,13,26,13,13,
    25,12,24,12,12, 23,11,22,11,11, 21,10,20,10,10, 19,9,18,9,9,
    17,8, 7,6,5,4,3,2,1};

__device__ __forceinline__ float fast_exp2(float x) {
#if __has_builtin(__builtin_amdgcn_exp2f)
    return __builtin_amdgcn_exp2f(x);
#else
    return exp2f(x);
#endif
}
__device__ __forceinline__ unsigned short f2bf(float f) { // RNE
    unsigned u = __float_as_uint(f);
    return (unsigned short)((u + 0x7fffu + ((u >> 16) & 1u)) >> 16);
}
__device__ __forceinline__ void ld8(const float* p, float* f) {
    float4 a = *(const float4*)p, b = *(const float4*)(p + 4);
    f[0]=a.x; f[1]=a.y; f[2]=a.z; f[3]=a.w; f[4]=b.x; f[5]=b.y; f[6]=b.z; f[7]=b.w;
}
__device__ __forceinline__ uint4 pack8(const float* f, float scale) {
    union { uint4 v; unsigned short s[8]; } w;
    #pragma unroll
    for (int j = 0; j < 8; j++) w.s[j] = f2bf(f[j] * scale);
    return w.v;
}
// combine high-16s of two floats into one dword: [lo16=a.hi16, hi16=b.hi16]
__device__ __forceinline__ unsigned packhi(float a, float b) {
#if __has_builtin(__builtin_amdgcn_perm)
    return __builtin_amdgcn_perm(__float_as_uint(b), __float_as_uint(a), 0x07060302u);
#else
    return (__float_as_uint(a) >> 16) | (__float_as_uint(b) & 0xffff0000u);
#endif
}

// ---- pre-pass: per block (st, bh): V 64x64 tile -> bf16 V^T tile, plus a
// 4096-elem chunk of Q (scaled) and K -> bf16.
__global__ __launch_bounds__(256) void prep(
    const float* __restrict__ Qf, const float* __restrict__ Kf,
    const float* __restrict__ Vf, unsigned short* __restrict__ qb,
    unsigned short* __restrict__ kb, unsigned short* __restrict__ vtb)
{
    const int st = blockIdx.x, bh = blockIdx.y;
    __shared__ unsigned short lt[64][LDP];
    const float* vp = Vf + ((size_t)bh * S_LEN + st * 64) * DHDIM;
    for (int c = threadIdx.x; c < 512; c += 256) {
        int s = c >> 3, d0 = (c & 7) * 8;
        float f[8]; ld8(vp + s * DHDIM + d0, f);
        #pragma unroll
        for (int j = 0; j < 8; j++) {
            int d = d0 + j;
            // XOR-swizzle the 16B chunk index with d>>3: write conflicts 8-way -> 2-way
            int col = (s & 7) | ((((s >> 3) ^ (d >> 3)) & 7) << 3);
            lt[d][col] = f2bf(f[j]);
        }
    }
    size_t off = ((size_t)(bh * 32 + st) * 4096) + (size_t)threadIdx.x * 16;
    float f[8];
    ld8(Qf + off, f);     *(uint4*)(qb + off)     = pack8(f, QSCALE);
    ld8(Qf + off + 8, f); *(uint4*)(qb + off + 8) = pack8(f, QSCALE);
    ld8(Kf + off, f);     *(uint4*)(kb + off)     = pack8(f, 1.0f);
    ld8(Kf + off + 8, f); *(uint4*)(kb + off + 8) = pack8(f, 1.0f);
    __syncthreads();
    unsigned short* op = vtb + (size_t)bh * DHDIM * S_LEN + st * 64;
    for (int c = threadIdx.x; c < 512; c += 256) {
        int d = c >> 3, q = c & 7;
        int colc = ((q ^ (d >> 3)) & 7) << 3;  // matching read-side swizzle
        *(uint4*)(op + (size_t)d * S_LEN + q * 8) = *(const uint4*)&lt[d][colc];
    }
}

// ---- main: block = (bh, rank). rank indexes the LPT table: either a half of
// a split row (qt>=16, writes unnormalized partial) or a whole short row
// (qt<16, writes normalized O directly).
__global__ __launch_bounds__(256) void fattn_splitk(
    const unsigned short* __restrict__ Qp, const unsigned short* __restrict__ Kp,
    const unsigned short* __restrict__ Vp,
    float* __restrict__ pO, float* __restrict__ pL, float* __restrict__ O)
{
    __shared__ unsigned short smem[192 * LDP]; // 27.6 KB -> 5 blocks/CU
    unsigned short (*ks)[LDP]  = (unsigned short(*)[LDP])smem;
    unsigned short (*vts)[LDP] = (unsigned short(*)[LDP])(smem + 64 * LDP);
    unsigned short (*qs)[LDP]  = (unsigned short(*)[LDP])(smem + 128 * LDP);
    unsigned short (*pst)[LDP] = qs; // overlay: wave w touches only rows w*16..+15

    const int bh   = blockIdx.x;           // 0..31
    const int rank = blockIdx.y;           // 0..47, longest-first
    const int qt   = T_QT[rank];
    const int k0   = T_K0[rank];
    const int k1   = T_K1[rank];
    const bool whole = (k1 - k0 == qt + 1);

    const int tid = threadIdx.x;
    const int wave = tid >> 6, lane = tid & 63;
    const int quad = lane >> 4, l16 = lane & 15;

    // ---- stage Q tile (bf16, pre-scaled by prep)
    {
        const unsigned short* src = Qp + ((size_t)bh * S_LEN + qt * 64) * DHDIM;
        for (int c = tid; c < 512; c += 256) {
            int row = c >> 3, c8 = (c & 7) * 8;
            *(uint4*)&qs[row][c8] = *(const uint4*)(src + row * DHDIM + c8);
        }
    }
    __syncthreads();

    const int prow = wave * 16 + l16; // this lane's q-row (transposed scheme)
    const bf16x8 bq0 = *(const bf16x8*)&qs[prow][quad * 8];
    const bf16x8 bq1 = *(const bf16x8*)&qs[prow][32 + quad * 8];

    bf16x8 ones;
    #pragma unroll
    for (int j = 0; j < 8; j++) ones[j] = (short)0x3F80; // bf16 1.0

    f32x4 of[4];
    f32x4 of_l = (f32x4){0.f, 0.f, 0.f, 0.f}; // ones-row * Pt = l per q-col
    #pragma unroll
    for (int n = 0; n < 4; n++) of[n] = (f32x4){0.f, 0.f, 0.f, 0.f};

    for (int kt = k0; kt < k1; kt++) {
        __syncthreads(); // prior iter done with ks/vts

        const unsigned short* ksrc = Kp + ((size_t)bh * S_LEN + kt * 64) * DHDIM;
        const unsigned short* vsrc = Vp + (size_t)bh * DHDIM * S_LEN + kt * 64;
        for (int c = tid; c < 512; c += 256) {
            int row = c >> 3, c8 = (c & 7) * 8;
            *(uint4*)&ks[row][c8]  = *(const uint4*)(ksrc + row * DHDIM + c8);
            *(uint4*)&vts[row][c8] = *(const uint4*)(vsrc + (size_t)row * S_LEN + c8);
        }
        __syncthreads();

        // ---- St tile n; C-init = -M2 folds the softmax subtract
        f32x4 sf[4];
        #pragma unroll
        for (int n = 0; n < 4; n++) {
            bf16x8 ak0 = *(const bf16x8*)&ks[n * 16 + l16][quad * 8];
            bf16x8 ak1 = *(const bf16x8*)&ks[n * 16 + l16][32 + quad * 8];
            sf[n] = (f32x4){-M2, -M2, -M2, -M2};
            sf[n] = __builtin_amdgcn_mfma_f32_16x16x32_bf16(ak0, bq0, sf[n], 0, 0, 0);
            sf[n] = __builtin_amdgcn_mfma_f32_16x16x32_bf16(ak1, bq1, sf[n], 0, 0, 0);
        }

        // ---- p = exp2(sf), causal zero (diag tile), pack Pt (l via MFMA below)
        const bool diag = (kt == qt);
        #pragma unroll
        for (int n = 0; n < 4; n++) {
            float p[4];
            #pragma unroll
            for (int r = 0; r < 4; r++) {
                p[r] = fast_exp2(sf[n][r]);
                if (diag && (n * 16 + quad * 4 + r > prow)) p[r] = 0.f;
            }
            uint2 dw;
            dw.x = packhi(p[0], p[1]); // bf16 truncation via byte-select
            dw.y = packhi(p[2], p[3]);
            *(uint2*)&pst[prow][n * 16 + quad * 4] = dw;
        }
        asm volatile("s_waitcnt lgkmcnt(0)" ::: "memory"); // wave-local Pt fence

        bf16x8 bp0 = *(const bf16x8*)&pst[prow][quad * 8];
        bf16x8 bp1 = *(const bf16x8*)&pst[prow][32 + quad * 8];
        of_l = __builtin_amdgcn_mfma_f32_16x16x32_bf16(ones, bp0, of_l, 0, 0, 0);
        of_l = __builtin_amdgcn_mfma_f32_16x16x32_bf16(ones, bp1, of_l, 0, 0, 0);
        #pragma unroll
        for (int n = 0; n < 4; n++) {
            bf16x8 av0 = *(const bf16x8*)&vts[n * 16 + l16][quad * 8];
            bf16x8 av1 = *(const bf16x8*)&vts[n * 16 + l16][32 + quad * 8];
            of[n] = __builtin_amdgcn_mfma_f32_16x16x32_bf16(av0, bp0, of[n], 0, 0, 0);
            of[n] = __builtin_amdgcn_mfma_f32_16x16x32_bf16(av1, bp1, of[n], 0, 0, 0);
        }
    }

    if (whole) {
        // short row: normalize and write O directly, no partial traffic
        const float inv = 1.f / of_l[0];
        float* op = O + ((size_t)bh * S_LEN + qt * 64 + prow) * DHDIM;
        #pragma unroll
        for (int n = 0; n < 4; n++)
            *(float4*)(op + n * 16 + quad * 4) = make_float4(
                of[n][0] * inv, of[n][1] * inv, of[n][2] * inv, of[n][3] * inv);
    } else {
        // split half: write unnormalized partial + per-row l (fixed-max softmax
        // => partials combine exactly by summation in the combine kernel)
        const int slot = ((bh * 16 + (qt - 16)) << 1) | (k0 != 0 ? 1 : 0);
        if (quad == 0) pL[slot * 64 + prow] = of_l[0];
        float* op = pO + (size_t)slot * 4096 + prow * 64;
        #pragma unroll
        for (int n = 0; n < 4; n++)
            *(float4*)(op + n * 16 + quad * 4) =
                make_float4(of[n][0], of[n][1], of[n][2], of[n][3]);
    }
}

// ---- combine: O = (Oa + Ob) / (la + lb), per (bh, qt) for qt in [16,31]
__global__ __launch_bounds__(256) void combine(
    const float* __restrict__ pO, const float* __restrict__ pL,
    float* __restrict__ O)
{
    const int qt = 16 + blockIdx.x, bh = blockIdx.y;
    const int sa = ((bh * 16 + (qt - 16)) << 1), sb = sa | 1;
    const float* A = pO + (size_t)sa * 4096;
    const float* B = pO + (size_t)sb * 4096;
    float* out = O + ((size_t)bh * S_LEN + qt * 64) * DHDIM;
    #pragma unroll
    for (int k = 0; k < 4; k++) {
        int c = threadIdx.x + k * 256;     // float4 chunk 0..1023
        int row = c >> 4;
        float inv = 1.f / (pL[sa * 64 + row] + pL[sb * 64 + row]);
        float4 a = *(const float4*)(A + c * 4);
        float4 b = *(const float4*)(B + c * 4);
        *(float4*)(out + c * 4) = make_float4(
            (a.x + b.x) * inv, (a.y + b.y) * inv,
            (a.z + b.z) * inv, (a.w + b.w) * inv);
    }
}

// ---- fallback kernels (whole-row blocks), used when ws too small
template <bool PRE>
__global__ __launch_bounds__(256) void fattn_kernel(
    const void* __restrict__ Qp, const void* __restrict__ Kp,
    const void* __restrict__ Vp, float* __restrict__ O)
{
    __shared__ unsigned short smem[192 * LDP];
    unsigned short (*ks)[LDP]  = (unsigned short(*)[LDP])smem;
    unsigned short (*vts)[LDP] = (unsigned short(*)[LDP])(smem + 64 * LDP);
    unsigned short (*qs)[LDP]  = (unsigned short(*)[LDP])(smem + 128 * LDP);
    unsigned short (*pst)[LDP] = qs;

    const int id = blockIdx.y * 32 + blockIdx.x;
    const int g  = id >> 8;
    const int r8 = id & 255;
    const int bh = r8 >> 3;
    const int s8 = r8 & 7;
    const int qt = (g == 0) ? 31 - 2 * s8 : (g == 1) ? 2 * s8
                 : (g == 2) ? 30 - 2 * s8 : 2 * s8 + 1;

    const int tid = threadIdx.x;
    const int wave = tid >> 6, lane = tid & 63;
    const int quad = lane >> 4, l16 = lane & 15;

    if constexpr (PRE) {
        const unsigned short* src = (const unsigned short*)Qp
            + ((size_t)bh * S_LEN + qt * 64) * DHDIM;
        for (int c = tid; c < 512; c += 256) {
            int row = c >> 3, c8 = (c & 7) * 8;
            *(uint4*)&qs[row][c8] = *(const uint4*)(src + row * DHDIM + c8);
        }
    } else {
        const float* src = (const float*)Qp + ((size_t)bh * S_LEN + qt * 64) * DHDIM;
        for (int c = tid; c < 512; c += 256) {
            int row = c >> 3, c8 = (c & 7) * 8;
            float f[8]; ld8(src + row * DHDIM + c8, f);
            *(uint4*)&qs[row][c8] = pack8(f, QSCALE);
        }
    }
    __syncthreads();

    const int prow = wave * 16 + l16;
    const bf16x8 bq0 = *(const bf16x8*)&qs[prow][quad * 8];
    const bf16x8 bq1 = *(const bf16x8*)&qs[prow][32 + quad * 8];

    float l_p = 0.f;
    f32x4 of[4];
    #pragma unroll
    for (int n = 0; n < 4; n++) of[n] = (f32x4){0.f, 0.f, 0.f, 0.f};

    for (int kt = 0; kt <= qt; kt++) {
        __syncthreads();
        if constexpr (PRE) {
            const unsigned short* ksrc = (const unsigned short*)Kp
                + ((size_t)bh * S_LEN + kt * 64) * DHDIM;
            const unsigned short* vsrc = (const unsigned short*)Vp
                + (size_t)bh * DHDIM * S_LEN + kt * 64;
            for (int c = tid; c < 512; c += 256) {
                int row = c >> 3, c8 = (c & 7) * 8;
                *(uint4*)&ks[row][c8]  = *(const uint4*)(ksrc + row * DHDIM + c8);
                *(uint4*)&vts[row][c8] = *(const uint4*)(vsrc + (size_t)row * S_LEN + c8);
            }
        } else {
            const float* ksrc = (const float*)Kp + ((size_t)bh * S_LEN + kt * 64) * DHDIM;
            const float* vsrc = (const float*)Vp + ((size_t)bh * S_LEN + kt * 64) * DHDIM;
            for (int c = tid; c < 512; c += 256) {
                int row = c >> 3, c8 = (c & 7) * 8;
                float f[8];
                ld8(ksrc + row * DHDIM + c8, f);
                *(uint4*)&ks[row][c8] = pack8(f, 1.0f);
                ld8(vsrc + row * DHDIM + c8, f);
                #pragma unroll
                for (int j = 0; j < 8; j++) vts[c8 + j][row] = f2bf(f[j]);
            }
        }
        __syncthreads();

        f32x4 sf[4];
        #pragma unroll
        for (int n = 0; n < 4; n++) {
            bf16x8 ak0 = *(const bf16x8*)&ks[n * 16 + l16][quad * 8];
            bf16x8 ak1 = *(const bf16x8*)&ks[n * 16 + l16][32 + quad * 8];
            sf[n] = (f32x4){-M2, -M2, -M2, -M2};
            sf[n] = __builtin_amdgcn_mfma_f32_16x16x32_bf16(ak0, bq0, sf[n], 0, 0, 0);
            sf[n] = __builtin_amdgcn_mfma_f32_16x16x32_bf16(ak1, bq1, sf[n], 0, 0, 0);
        }

        const bool diag = (kt == qt);
        #pragma unroll
        for (int n = 0; n < 4; n++) {
            float p[4];
            #pragma unroll
            for (int r = 0; r < 4; r++) {
                p[r] = fast_exp2(sf[n][r]);
                if (diag && (n * 16 + quad * 4 + r > prow)) p[r] = 0.f;
                l_p += p[r];
            }
            uint2 dw;
            dw.x = packhi(p[0], p[1]);
            dw.y = packhi(p[2], p[3]);
            *(uint2*)&pst[prow][n * 16 + quad * 4] = dw;
        }
        asm volatile("s_waitcnt lgkmcnt(0)" ::: "memory");

        bf16x8 bp0 = *(const bf16x8*)&pst[prow][quad * 8];
        bf16x8 bp1 = *(const bf16x8*)&pst[prow][32 + quad * 8];
        #pragma unroll
        for (int n = 0; n < 4; n++) {
            bf16x8 av0 = *(const bf16x8*)&vts[n * 16 + l16][quad * 8];
            bf16x8 av1 = *(const bf16x8*)&vts[n * 16 + l16][32 + quad * 8];
            of[n] = __builtin_amdgcn_mfma_f32_16x16x32_bf16(av0, bp0, of[n], 0, 0, 0);
            of[n] = __builtin_amdgcn_mfma_f32_16x16x32_bf16(av1, bp1, of[n], 0, 0, 0);
        }
    }

    l_p += __shfl_xor(l_p, 16);
    l_p += __shfl_xor(l_p, 32);
    const float inv = 1.f / l_p;
    float* op = O + ((size_t)bh * S_LEN + qt * 64 + prow) * DHDIM;
    #pragma unroll
    for (int n = 0; n < 4; n++)
        *(float4*)(op + n * 16 + quad * 4) = make_float4(
            of[n][0] * inv, of[n][1] * inv, of[n][2] * inv, of[n][3] * inv);
}

extern "C" void kernel_launch(void* const* d_in, const int* in_sizes, int n_in,
                              void* d_out, int out_size, void* d_ws, size_t ws_size,
                              hipStream_t stream) {
    const float* Q = (const float*)d_in[0];
    const float* K = (const float*)d_in[1];
    const float* V = (const float*)d_in[2];
    // d_in[3] = causal mask: analytic, not read.
    float* O = (float*)d_out;
    const size_t N = (size_t)NHEADS * S_LEN * DHDIM;      // 4,194,304 elems
    const size_t prepB  = 3 * N * sizeof(unsigned short); // 25.2 MB
    // 1024 partial slots (qt>=16 halves): O-partials + l
    const size_t partB  = (size_t)1024 * (4096 + 64) * sizeof(float); // 17.0 MB

    if (d_ws && ws_size >= prepB + partB) {
        unsigned short* qb  = (unsigned short*)d_ws;
        unsigned short* kb  = qb + N;
        unsigned short* vtb = kb + N;
        float* pO = (float*)((char*)d_ws + prepB);
        float* pL = pO + (size_t)1024 * 4096;
        prep<<<dim3(S_LEN / 64, NHEADS), 256, 0, stream>>>(Q, K, V, qb, kb, vtb);
        fattn_splitk<<<dim3(32, 48), 256, 0, stream>>>(qb, kb, vtb, pO, pL, O);
        combine<<<dim3(16, 32), 256, 0, stream>>>(pO, pL, O);
    } else if (d_ws && ws_size >= prepB) {
        unsigned short* qb  = (unsigned short*)d_ws;
        unsigned short* kb  = qb + N;
        unsigned short* vtb = kb + N;
        prep<<<dim3(S_LEN / 64, NHEADS), 256, 0, stream>>>(Q, K, V, qb, kb, vtb);
        fattn_kernel<true><<<dim3(32, 32), 256, 0, stream>>>(qb, kb, vtb, O);
    } else {
        fattn_kernel<false><<<dim3(32, 32), 256, 0, stream>>>(Q, K, V, O);
    }
}

// Round 3
// 140.685 us; speedup vs baseline: 3.0638x; 1.0291x over previous
//
#include <hip/hip_runtime.h>

// Causal MHA: B=2, H=16, S=2048, DH=64. fp32 in/out. bf16 MFMA inside.
// R12: T14 async-STAGE prefetch in splitk. R11 counters showed the latency
// regime: MfmaUtil 16%, VALUBusy 29%, HBM 11%, Occ 35% -- nothing saturated;
// the per-tile serial chain {global load -> LDS -> barrier -> compute} exposes
// ~400+ cyc of load latency per K-tile at only 5 blocks/CU. Fix: prefetch the
// NEXT K/V tile into registers (4x uint4/thread) immediately after writing the
// current tile to LDS; the loads' latency hides under the current tile's
// MFMA+exp2 phase. Also: prep V-transpose now writes row-PAIRS as dwords
// (8 ds_write_b32 vs 16 ds_write_b16, RNE kept, 2-way-free dword swizzle).
// Kept from R11: selective split-k (qt>=16 split in two, qt<16 whole, 1536
// blocks, static LPT), l via ones-row MFMA, fast_exp2, fixed-max softmax
// (partials combine EXACTLY), transposed GEMMs (St=K*Q^T, Ot=V^T*Pt), -M2 in
// MFMA C-init, v_perm Pt pack, LDP=72, prep (bf16 Q*0.125*log2e, K, V^T),
// analytic causal mask, wave-local lgkmcnt fence. NOT chasing the 6M LDS bank
// conflicts: latency-bound regime => conflict fix would be a null (T2 gate).

#define S_LEN  2048
#define DHDIM  64
#define NHEADS 32   // B*H
#define LDP    72   // padded LDS row length in shorts (144B = 9*16B)
#define M2     23.083120654223414f   // 16 * log2(e)
#define QSCALE 0.18033688011117658f  // 0.125 * log2(e)

typedef __attribute__((ext_vector_type(8))) short bf16x8;
typedef __attribute__((ext_vector_type(4))) float f32x4;

// static LPT schedule: 48 items per bh, descending length.
// splits for qt in [16,31] (kmid=(qt+2)>>1), wholes for qt in [0,15].
__device__ __constant__ unsigned char T_QT[48] = {
    31,31,30,15, 30,29,29,28,14, 28,27,27,26,13, 26,25,25,24,12,
    24,23,23,22,11, 22,21,21,20,10, 20,19,19,18,9, 18,17,17,16,8,
    16,7, 6,5,4,3,2,1,0};
__device__ __constant__ unsigned char T_K0[48] = {
    0,16,0,0, 16,0,15,0,0, 15,0,14,0,0, 14,0,13,0,0,
    13,0,12,0,0, 12,0,11,0,0, 11,0,10,0,0, 10,0,9,0,0,
    9,0, 0,0,0,0,0,0,0};
__device__ __constant__ unsigned char T_K1[48] = {
    16,32,16,16, 31,15,30,15,15, 29,14,28,14,14, 27,13,26,13,13,
    25,12,24,12,12, 23,11,22,11,11, 21,10,20,10,10, 19,9,18,9,9,
    17,8, 7,6,5,4,3,2,1};

__device__ __forceinline__ float fast_exp2(float x) {
#if __has_builtin(__builtin_amdgcn_exp2f)
    return __builtin_amdgcn_exp2f(x);
#else
    return exp2f(x);
#endif
}
__device__ __forceinline__ unsigned short f2bf(float f) { // RNE
    unsigned u = __float_as_uint(f);
    return (unsigned short)((u + 0x7fffu + ((u >> 16) & 1u)) >> 16);
}
__device__ __forceinline__ void ld8(const float* p, float* f) {
    float4 a = *(const float4*)p, b = *(const float4*)(p + 4);
    f[0]=a.x; f[1]=a.y; f[2]=a.z; f[3]=a.w; f[4]=b.x; f[5]=b.y; f[6]=b.z; f[7]=b.w;
}
__device__ __forceinline__ uint4 pack8(const float* f, float scale) {
    union { uint4 v; unsigned short s[8]; } w;
    #pragma unroll
    for (int j = 0; j < 8; j++) w.s[j] = f2bf(f[j] * scale);
    return w.v;
}
// combine high-16s of two floats into one dword: [lo16=a.hi16, hi16=b.hi16]
__device__ __forceinline__ unsigned packhi(float a, float b) {
#if __has_builtin(__builtin_amdgcn_perm)
    return __builtin_amdgcn_perm(__float_as_uint(b), __float_as_uint(a), 0x07060302u);
#else
    return (__float_as_uint(a) >> 16) | (__float_as_uint(b) & 0xffff0000u);
#endif
}

// ---- pre-pass: per block (st, bh): V 64x64 tile -> bf16 V^T tile, plus a
// 4096-elem chunk of Q (scaled) and K -> bf16.
__global__ __launch_bounds__(256) void prep(
    const float* __restrict__ Qf, const float* __restrict__ Kf,
    const float* __restrict__ Vf, unsigned short* __restrict__ qb,
    unsigned short* __restrict__ kb, unsigned short* __restrict__ vtb)
{
    const int st = blockIdx.x, bh = blockIdx.y;
    __shared__ unsigned lt32[64][LDP / 2];   // dword view: 36 dwords/row
    const float* vp = Vf + ((size_t)bh * S_LEN + st * 64) * DHDIM;
    {
        // thread c: rows s0=2*(c>>3), s0+1; d0=(c&7)*8. One pass, dword writes.
        const int c = threadIdx.x;
        const int sp = c >> 3;            // s-pair index 0..31
        const int d0 = (c & 7) * 8;
        float fa[8], fb[8];
        ld8(vp + (2 * sp) * DHDIM + d0, fa);
        ld8(vp + (2 * sp + 1) * DHDIM + d0, fb);
        #pragma unroll
        for (int j = 0; j < 8; j++) {
            int d = d0 + j;
            // dword-swizzle: colw = (sp&3) | (((sp>>2) ^ (d>>3)) & 7) << 2
            // bank spread 2-way (free); bijective in sp per d.
            int colw = (sp & 3) | ((((sp >> 2) ^ (d >> 3)) & 7) << 2);
            lt32[d][colw] = (unsigned)f2bf(fa[j]) | ((unsigned)f2bf(fb[j]) << 16);
        }
    }
    size_t off = ((size_t)(bh * 32 + st) * 4096) + (size_t)threadIdx.x * 16;
    float f[8];
    ld8(Qf + off, f);     *(uint4*)(qb + off)     = pack8(f, QSCALE);
    ld8(Qf + off + 8, f); *(uint4*)(qb + off + 8) = pack8(f, QSCALE);
    ld8(Kf + off, f);     *(uint4*)(kb + off)     = pack8(f, 1.0f);
    ld8(Kf + off + 8, f); *(uint4*)(kb + off + 8) = pack8(f, 1.0f);
    __syncthreads();
    unsigned short* op = vtb + (size_t)bh * DHDIM * S_LEN + st * 64;
    for (int c = threadIdx.x; c < 512; c += 256) {
        int d = c >> 3, q = c & 7;
        // read 4 consecutive dwords (8 shorts, s = q*8..q*8+7):
        // sp = 4q..4q+3 share sp>>2 == q  ->  base colw = (4q ^ ...) ... here
        // (sp&3)=0..3 contiguous, high bits ((q ^ (d>>3)) & 7) << 2.
        int colw = ((q ^ (d >> 3)) & 7) << 2;
        // dword base within row: (sp&3)=0 start; 4 dwords contiguous
        *(uint4*)(op + (size_t)d * S_LEN + q * 8) = *(const uint4*)&lt32[d][colw & ~3 ? colw : colw];
    }
}

// ---- main: block = (bh, rank). rank indexes the LPT table: either a half of
// a split row (qt>=16, writes unnormalized partial) or a whole short row
// (qt<16, writes normalized O directly). NEW: next-tile register prefetch.
__global__ __launch_bounds__(256) void fattn_splitk(
    const unsigned short* __restrict__ Qp, const unsigned short* __restrict__ Kp,
    const unsigned short* __restrict__ Vp,
    float* __restrict__ pO, float* __restrict__ pL, float* __restrict__ O)
{
    __shared__ unsigned short smem[192 * LDP]; // 27.6 KB -> 5 blocks/CU
    unsigned short (*ks)[LDP]  = (unsigned short(*)[LDP])smem;
    unsigned short (*vts)[LDP] = (unsigned short(*)[LDP])(smem + 64 * LDP);
    unsigned short (*qs)[LDP]  = (unsigned short(*)[LDP])(smem + 128 * LDP);
    unsigned short (*pst)[LDP] = qs; // overlay: wave w touches only rows w*16..+15

    const int bh   = blockIdx.x;           // 0..31
    const int rank = blockIdx.y;           // 0..47, longest-first
    const int qt   = T_QT[rank];
    const int k0   = T_K0[rank];
    const int k1   = T_K1[rank];
    const bool whole = (k1 - k0 == qt + 1);

    const int tid = threadIdx.x;
    const int wave = tid >> 6, lane = tid & 63;
    const int quad = lane >> 4, l16 = lane & 15;

    // ---- stage Q tile (bf16, pre-scaled by prep)
    {
        const unsigned short* src = Qp + ((size_t)bh * S_LEN + qt * 64) * DHDIM;
        for (int c = tid; c < 512; c += 256) {
            int row = c >> 3, c8 = (c & 7) * 8;
            *(uint4*)&qs[row][c8] = *(const uint4*)(src + row * DHDIM + c8);
        }
    }
    __syncthreads();

    const int prow = wave * 16 + l16; // this lane's q-row (transposed scheme)
    const bf16x8 bq0 = *(const bf16x8*)&qs[prow][quad * 8];
    const bf16x8 bq1 = *(const bf16x8*)&qs[prow][32 + quad * 8];

    bf16x8 ones;
    #pragma unroll
    for (int j = 0; j < 8; j++) ones[j] = (short)0x3F80; // bf16 1.0

    f32x4 of[4];
    f32x4 of_l = (f32x4){0.f, 0.f, 0.f, 0.f}; // ones-row * Pt = l per q-col
    #pragma unroll
    for (int n = 0; n < 4; n++) of[n] = (f32x4){0.f, 0.f, 0.f, 0.f};

    // ---- T14 prefetch: staging registers for the next K/V tile
    const unsigned short* Kbh = Kp + (size_t)bh * S_LEN * DHDIM;
    const unsigned short* Vbh = Vp + (size_t)bh * DHDIM * S_LEN;
    const int sr = tid >> 3, sc = (tid & 7) * 8;   // rows sr, sr+32
    uint4 kr0, kr1, vr0, vr1;
    {
        const unsigned short* ksrc = Kbh + (size_t)k0 * 64 * DHDIM;
        const unsigned short* vsrc = Vbh + k0 * 64;
        kr0 = *(const uint4*)(ksrc + sr * DHDIM + sc);
        kr1 = *(const uint4*)(ksrc + (sr + 32) * DHDIM + sc);
        vr0 = *(const uint4*)(vsrc + (size_t)sr * S_LEN + sc);
        vr1 = *(const uint4*)(vsrc + (size_t)(sr + 32) * S_LEN + sc);
    }

    for (int kt = k0; kt < k1; kt++) {
        __syncthreads(); // prior iter's compute done with ks/vts

        // write current prefetched tile to LDS (vmcnt wait folds in here)
        *(uint4*)&ks[sr][sc]       = kr0;
        *(uint4*)&ks[sr + 32][sc]  = kr1;
        *(uint4*)&vts[sr][sc]      = vr0;
        *(uint4*)&vts[sr + 32][sc] = vr1;

        // issue next tile's global loads; latency hides under compute below
        if (kt + 1 < k1) {
            const unsigned short* ksrc = Kbh + (size_t)(kt + 1) * 64 * DHDIM;
            const unsigned short* vsrc = Vbh + (kt + 1) * 64;
            kr0 = *(const uint4*)(ksrc + sr * DHDIM + sc);
            kr1 = *(const uint4*)(ksrc + (sr + 32) * DHDIM + sc);
            vr0 = *(const uint4*)(vsrc + (size_t)sr * S_LEN + sc);
            vr1 = *(const uint4*)(vsrc + (size_t)(sr + 32) * S_LEN + sc);
        }
        __syncthreads();

        // ---- St tile n; C-init = -M2 folds the softmax subtract
        f32x4 sf[4];
        #pragma unroll
        for (int n = 0; n < 4; n++) {
            bf16x8 ak0 = *(const bf16x8*)&ks[n * 16 + l16][quad * 8];
            bf16x8 ak1 = *(const bf16x8*)&ks[n * 16 + l16][32 + quad * 8];
            sf[n] = (f32x4){-M2, -M2, -M2, -M2};
            sf[n] = __builtin_amdgcn_mfma_f32_16x16x32_bf16(ak0, bq0, sf[n], 0, 0, 0);
            sf[n] = __builtin_amdgcn_mfma_f32_16x16x32_bf16(ak1, bq1, sf[n], 0, 0, 0);
        }

        // ---- p = exp2(sf), causal zero (diag tile), pack Pt (l via MFMA below)
        const bool diag = (kt == qt);
        #pragma unroll
        for (int n = 0; n < 4; n++) {
            float p[4];
            #pragma unroll
            for (int r = 0; r < 4; r++) {
                p[r] = fast_exp2(sf[n][r]);
                if (diag && (n * 16 + quad * 4 + r > prow)) p[r] = 0.f;
            }
            uint2 dw;
            dw.x = packhi(p[0], p[1]); // bf16 truncation via byte-select
            dw.y = packhi(p[2], p[3]);
            *(uint2*)&pst[prow][n * 16 + quad * 4] = dw;
        }
        asm volatile("s_waitcnt lgkmcnt(0)" ::: "memory"); // wave-local Pt fence

        bf16x8 bp0 = *(const bf16x8*)&pst[prow][quad * 8];
        bf16x8 bp1 = *(const bf16x8*)&pst[prow][32 + quad * 8];
        of_l = __builtin_amdgcn_mfma_f32_16x16x32_bf16(ones, bp0, of_l, 0, 0, 0);
        of_l = __builtin_amdgcn_mfma_f32_16x16x32_bf16(ones, bp1, of_l, 0, 0, 0);
        #pragma unroll
        for (int n = 0; n < 4; n++) {
            bf16x8 av0 = *(const bf16x8*)&vts[n * 16 + l16][quad * 8];
            bf16x8 av1 = *(const bf16x8*)&vts[n * 16 + l16][32 + quad * 8];
            of[n] = __builtin_amdgcn_mfma_f32_16x16x32_bf16(av0, bp0, of[n], 0, 0, 0);
            of[n] = __builtin_amdgcn_mfma_f32_16x16x32_bf16(av1, bp1, of[n], 0, 0, 0);
        }
    }

    if (whole) {
        // short row: normalize and write O directly, no partial traffic
        const float inv = 1.f / of_l[0];
        float* op = O + ((size_t)bh * S_LEN + qt * 64 + prow) * DHDIM;
        #pragma unroll
        for (int n = 0; n < 4; n++)
            *(float4*)(op + n * 16 + quad * 4) = make_float4(
                of[n][0] * inv, of[n][1] * inv, of[n][2] * inv, of[n][3] * inv);
    } else {
        // split half: write unnormalized partial + per-row l (fixed-max softmax
        // => partials combine exactly by summation in the combine kernel)
        const int slot = ((bh * 16 + (qt - 16)) << 1) | (k0 != 0 ? 1 : 0);
        if (quad == 0) pL[slot * 64 + prow] = of_l[0];
        float* op = pO + (size_t)slot * 4096 + prow * 64;
        #pragma unroll
        for (int n = 0; n < 4; n++)
            *(float4*)(op + n * 16 + quad * 4) =
                make_float4(of[n][0], of[n][1], of[n][2], of[n][3]);
    }
}

// ---- combine: O = (Oa + Ob) / (la + lb), per (bh, qt) for qt in [16,31]
__global__ __launch_bounds__(256) void combine(
    const float* __restrict__ pO, const float* __restrict__ pL,
    float* __restrict__ O)
{
    const int qt = 16 + blockIdx.x, bh = blockIdx.y;
    const int sa = ((bh * 16 + (qt - 16)) << 1), sb = sa | 1;
    const float* A = pO + (size_t)sa * 4096;
    const float* B = pO + (size_t)sb * 4096;
    float* out = O + ((size_t)bh * S_LEN + qt * 64) * DHDIM;
    #pragma unroll
    for (int k = 0; k < 4; k++) {
        int c = threadIdx.x + k * 256;     // float4 chunk 0..1023
        int row = c >> 4;
        float inv = 1.f / (pL[sa * 64 + row] + pL[sb * 64 + row]);
        float4 a = *(const float4*)(A + c * 4);
        float4 b = *(const float4*)(B + c * 4);
        *(float4*)(out + c * 4) = make_float4(
            (a.x + b.x) * inv, (a.y + b.y) * inv,
            (a.z + b.z) * inv, (a.w + b.w) * inv);
    }
}

// ---- fallback kernels (whole-row blocks), used when ws too small
template <bool PRE>
__global__ __launch_bounds__(256) void fattn_kernel(
    const void* __restrict__ Qp, const void* __restrict__ Kp,
    const void* __restrict__ Vp, float* __restrict__ O)
{
    __shared__ unsigned short smem[192 * LDP];
    unsigned short (*ks)[LDP]  = (unsigned short(*)[LDP])smem;
    unsigned short (*vts)[LDP] = (unsigned short(*)[LDP])(smem + 64 * LDP);
    unsigned short (*qs)[LDP]  = (unsigned short(*)[LDP])(smem + 128 * LDP);
    unsigned short (*pst)[LDP] = qs;

    const int id = blockIdx.y * 32 + blockIdx.x;
    const int g  = id >> 8;
    const int r8 = id & 255;
    const int bh = r8 >> 3;
    const int s8 = r8 & 7;
    const int qt = (g == 0) ? 31 - 2 * s8 : (g == 1) ? 2 * s8
                 : (g == 2) ? 30 - 2 * s8 : 2 * s8 + 1;

    const int tid = threadIdx.x;
    const int wave = tid >> 6, lane = tid & 63;
    const int quad = lane >> 4, l16 = lane & 15;

    if constexpr (PRE) {
        const unsigned short* src = (const unsigned short*)Qp
            + ((size_t)bh * S_LEN + qt * 64) * DHDIM;
        for (int c = tid; c < 512; c += 256) {
            int row = c >> 3, c8 = (c & 7) * 8;
            *(uint4*)&qs[row][c8] = *(const uint4*)(src + row * DHDIM + c8);
        }
    } else {
        const float* src = (const float*)Qp + ((size_t)bh * S_LEN + qt * 64) * DHDIM;
        for (int c = tid; c < 512; c += 256) {
            int row = c >> 3, c8 = (c & 7) * 8;
            float f[8]; ld8(src + row * DHDIM + c8, f);
            *(uint4*)&qs[row][c8] = pack8(f, QSCALE);
        }
    }
    __syncthreads();

    const int prow = wave * 16 + l16;
    const bf16x8 bq0 = *(const bf16x8*)&qs[prow][quad * 8];
    const bf16x8 bq1 = *(const bf16x8*)&qs[prow][32 + quad * 8];

    float l_p = 0.f;
    f32x4 of[4];
    #pragma unroll
    for (int n = 0; n < 4; n++) of[n] = (f32x4){0.f, 0.f, 0.f, 0.f};

    for (int kt = 0; kt <= qt; kt++) {
        __syncthreads();
        if constexpr (PRE) {
            const unsigned short* ksrc = (const unsigned short*)Kp
                + ((size_t)bh * S_LEN + kt * 64) * DHDIM;
            const unsigned short* vsrc = (const unsigned short*)Vp
                + (size_t)bh * DHDIM * S_LEN + kt * 64;
            for (int c = tid; c < 512; c += 256) {
                int row = c >> 3, c8 = (c & 7) * 8;
                *(uint4*)&ks[row][c8]  = *(const uint4*)(ksrc + row * DHDIM + c8);
                *(uint4*)&vts[row][c8] = *(const uint4*)(vsrc + (size_t)row * S_LEN + c8);
            }
        } else {
            const float* ksrc = (const float*)Kp + ((size_t)bh * S_LEN + kt * 64) * DHDIM;
            const float* vsrc = (const float*)Vp + ((size_t)bh * S_LEN + kt * 64) * DHDIM;
            for (int c = tid; c < 512; c += 256) {
                int row = c >> 3, c8 = (c & 7) * 8;
                float f[8];
                ld8(ksrc + row * DHDIM + c8, f);
                *(uint4*)&ks[row][c8] = pack8(f, 1.0f);
                ld8(vsrc + row * DHDIM + c8, f);
                #pragma unroll
                for (int j = 0; j < 8; j++) vts[c8 + j][row] = f2bf(f[j]);
            }
        }
        __syncthreads();

        f32x4 sf[4];
        #pragma unroll
        for (int n = 0; n < 4; n++) {
            bf16x8 ak0 = *(const bf16x8*)&ks[n * 16 + l16][quad * 8];
            bf16x8 ak1 = *(const bf16x8*)&ks[n * 16 + l16][32 + quad * 8];
            sf[n] = (f32x4){-M2, -M2, -M2, -M2};
            sf[n] = __builtin_amdgcn_mfma_f32_16x16x32_bf16(ak0, bq0, sf[n], 0, 0, 0);
            sf[n] = __builtin_amdgcn_mfma_f32_16x16x32_bf16(ak1, bq1, sf[n], 0, 0, 0);
        }

        const bool diag = (kt == qt);
        #pragma unroll
        for (int n = 0; n < 4; n++) {
            float p[4];
            #pragma unroll
            for (int r = 0; r < 4; r++) {
                p[r] = fast_exp2(sf[n][r]);
                if (diag && (n * 16 + quad * 4 + r > prow)) p[r] = 0.f;
                l_p += p[r];
            }
            uint2 dw;
            dw.x = packhi(p[0], p[1]);
            dw.y = packhi(p[2], p[3]);
            *(uint2*)&pst[prow][n * 16 + quad * 4] = dw;
        }
        asm volatile("s_waitcnt lgkmcnt(0)" ::: "memory");

        bf16x8 bp0 = *(const bf16x8*)&pst[prow][quad * 8];
        bf16x8 bp1 = *(const bf16x8*)&pst[prow][32 + quad * 8];
        #pragma unroll
        for (int n = 0; n < 4; n++) {
            bf16x8 av0 = *(const bf16x8*)&vts[n * 16 + l16][quad * 8];
            bf16x8 av1 = *(const bf16x8*)&vts[n * 16 + l16][32 + quad * 8];
            of[n] = __builtin_amdgcn_mfma_f32_16x16x32_bf16(av0, bp0, of[n], 0, 0, 0);
            of[n] = __builtin_amdgcn_mfma_f32_16x16x32_bf16(av1, bp1, of[n], 0, 0, 0);
        }
    }

    l_p += __shfl_xor(l_p, 16);
    l_p += __shfl_xor(l_p, 32);
    const float inv = 1.f / l_p;
    float* op = O + ((size_t)bh * S_LEN + qt * 64 + prow) * DHDIM;
    #pragma unroll
    for (int n = 0; n < 4; n++)
        *(float4*)(op + n * 16 + quad * 4) = make_float4(
            of[n][0] * inv, of[n][1] * inv, of[n][2] * inv, of[n][3] * inv);
}

extern "C" void kernel_launch(void* const* d_in, const int* in_sizes, int n_in,
                              void* d_out, int out_size, void* d_ws, size_t ws_size,
                              hipStream_t stream) {
    const float* Q = (const float*)d_in[0];
    const float* K = (const float*)d_in[1];
    const float* V = (const float*)d_in[2];
    // d_in[3] = causal mask: analytic, not read.
    float* O = (float*)d_out;
    const size_t N = (size_t)NHEADS * S_LEN * DHDIM;      // 4,194,304 elems
    const size_t prepB  = 3 * N * sizeof(unsigned short); // 25.2 MB
    // 1024 partial slots (qt>=16 halves): O-partials + l
    const size_t partB  = (size_t)1024 * (4096 + 64) * sizeof(float); // 17.0 MB

    if (d_ws && ws_size >= prepB + partB) {
        unsigned short* qb  = (unsigned short*)d_ws;
        unsigned short* kb  = qb + N;
        unsigned short* vtb = kb + N;
        float* pO = (float*)((char*)d_ws + prepB);
        float* pL = pO + (size_t)1024 * 4096;
        prep<<<dim3(S_LEN / 64, NHEADS), 256, 0, stream>>>(Q, K, V, qb, kb, vtb);
        fattn_splitk<<<dim3(32, 48), 256, 0, stream>>>(qb, kb, vtb, pO, pL, O);
        combine<<<dim3(16, 32), 256, 0, stream>>>(pO, pL, O);
    } else if (d_ws && ws_size >= prepB) {
        unsigned short* qb  = (unsigned short*)d_ws;
        unsigned short* kb  = qb + N;
        unsigned short* vtb = kb + N;
        prep<<<dim3(S_LEN / 64, NHEADS), 256, 0, stream>>>(Q, K, V, qb, kb, vtb);
        fattn_kernel<true><<<dim3(32, 32), 256, 0, stream>>>(qb, kb, vtb, O);
    } else {
        fattn_kernel<false><<<dim3(32, 32), 256, 0, stream>>>(Q, K, V, O);
    }
}